// Round 6
// baseline (411.018 us; speedup 1.0000x reference)
//
#include <hip/hip_runtime.h>
#include <stdint.h>
#include <math.h>

// OTLoss: ft(4096x1024), fs(4096x1024) fp32 -> (loss, P[4096x4096], M[4096x4096])
//
// Pipeline:
//  1) norm_rows2 (fused): row-normalize ft,fs -> bf16 A,B; block 0 zeroes bar state
//  2) gemm_bt: M_raw = A @ B^T (mfma 16x16x32, 128x128 tiles, global_load_lds,
//     DOUBLE-BUFFERED LDS: prefetch(k+1) issued before compute(k), single
//     vmcnt(0)+s_barrier per K-step -- r0-r4 exposed full load latency every
//     step, MfmaUtil 9.3%). M_raw goes to the P output slot (P unused until the
//     end). Epilogue: per-block sum/sq partials + per-(bn,waveN) row maxes
//     (plain stores; contended atomics removed in r3).
//  3) row_stats: rowmax[4096] from rmPart; mean/inv_std (ddof=1, double) -> scal
//  4) sinkhorn_full (PLAIN launch, 256 blocks x 512 thr, <=256 VGPR -> 1/CU,
//     all co-resident; plain launch saves ~90us vs cooperative, r2/r3):
//     DUAL-STRIP registers: block b holds K row-strip [16b,16b+16) (kreg) AND
//     K col-strip cols [16b,16b+16) (kcol), each 64 VGPR fp16. Per iter:
//       u = r/(Krow v) by owner block -> u[4096]   (32 KB exchange, was 4 MB tg)
//       tree-barrier; t = Kcol^T u by owner block -> t[4096]; tree-barrier;
//       maxdev computed REDUNDANTLY per block (512 thr x 8 cols cover all 4096
//       -> bit-identical md in every block, no devArr exchange).
//     Sync = r2/r3-PROVEN 2-level tree barrier (~2.2us). r4's flat-flag poll
//     regressed (poll self-congestion); r5's p2p flags never ran (container
//     failure, infra-vs-hang unresolved) -> this round uses only proven sync.
//     - phase0: kcol from raw-M col-stripe; kreg from raw-M row-strip;
//       standardized M written to the M slot (raw stays in P slot: no race)
//     - final: w = 1/(Kv); s = K^T w; P_ij = K_ij*w_i/s_j overwrites raw M;
//       loss = ||P-I||_F via lossArr + barrier, block 0 writes out[0]

#define NN 4096
#define DIM 1024
#define OT_ITERS 20
#define OT_EPS_F 1e-6f
#define RC (1.0f/4096.0f)
#define RPB 16   // rows/cols owned per block
#define SBT 512  // sinkhorn block threads

typedef __bf16 bf16_t;
typedef _Float16 half_t;
typedef __bf16 bf16x8 __attribute__((ext_vector_type(8)));
typedef _Float16 halfx8 __attribute__((ext_vector_type(8)));
typedef float floatx4 __attribute__((ext_vector_type(4)));

typedef __attribute__((address_space(1))) void gv_t;
typedef __attribute__((address_space(3))) void lv_t;

// async global->LDS, 16B per lane; lds dst = wave-uniform base, HW adds lane*16
__device__ __forceinline__ void gld_lds16(const void* g, void* lds_uniform) {
  uint32_t loff = (uint32_t)(uintptr_t)lds_uniform;
  loff = (uint32_t)__builtin_amdgcn_readfirstlane((int)loff);
  __builtin_amdgcn_global_load_lds((gv_t*)(uintptr_t)g, (lv_t*)(uintptr_t)loff, 16, 0, 0);
}

// ---- 2-level tree grid barrier (r2/r3-proven) ------------------------------
// bar layout (uint32): cnt[grp] at grp*64 (grp<8, separate lines), root at 512,
// gen at 576. Zeroed each launch by norm_rows2 block 0.
__device__ __forceinline__ void gbar(uint32_t* bar, uint32_t g) {
  __syncthreads();  // compiler drains vmcnt before s_barrier -> stores visible
  if (threadIdx.x == 0) {
    uint32_t* cnt = bar + ((blockIdx.x >> 5) * 64);
    uint32_t* root = bar + 512;
    uint32_t* gen = bar + 576;
    if (__hip_atomic_fetch_add(cnt, 1u, __ATOMIC_RELEASE, __HIP_MEMORY_SCOPE_AGENT) == 31u) {
      __hip_atomic_store(cnt, 0u, __ATOMIC_RELAXED, __HIP_MEMORY_SCOPE_AGENT);
      if (__hip_atomic_fetch_add(root, 1u, __ATOMIC_ACQ_REL, __HIP_MEMORY_SCOPE_AGENT) == 7u) {
        __hip_atomic_store(root, 0u, __ATOMIC_RELAXED, __HIP_MEMORY_SCOPE_AGENT);
        __hip_atomic_store(gen, g, __ATOMIC_RELEASE, __HIP_MEMORY_SCOPE_AGENT);
      }
    }
    while (__hip_atomic_load(gen, __ATOMIC_RELAXED, __HIP_MEMORY_SCOPE_AGENT) < g)
      __builtin_amdgcn_s_sleep(1);
    __builtin_amdgcn_fence(__ATOMIC_ACQUIRE, "agent");
  }
  __syncthreads();
}

// ---------------- fused row normalize (ft and fs) + bar init ----------------
__global__ __launch_bounds__(256) void norm_rows2(const float* __restrict__ ft,
                                                  const float* __restrict__ fs,
                                                  bf16_t* __restrict__ A,
                                                  bf16_t* __restrict__ B,
                                                  uint32_t* __restrict__ bar) {
  int gb = blockIdx.x;  // 0..2047
  const float* X = (gb < 1024) ? ft : fs;
  bf16_t* Y = (gb < 1024) ? A : B;
  int bb = gb & 1023;
  int tid = threadIdx.x;
  int wave = tid >> 6, lane = tid & 63;
  int row = bb * 4 + wave;
  const float* xr = X + (size_t)row * DIM;
  float xv[16];
  float ss = 0.f;
#pragma unroll
  for (int k = 0; k < 16; k++) { xv[k] = xr[lane + 64 * k]; ss += xv[k] * xv[k]; }
#pragma unroll
  for (int off = 1; off < 64; off <<= 1) ss += __shfl_xor(ss, off, 64);
  float inv = rsqrtf(ss);  // norm ~ 32 >> 1e-12 floor, floor never binds
  bf16_t* yr = Y + (size_t)row * DIM;
#pragma unroll
  for (int k = 0; k < 16; k++) yr[lane + 64 * k] = (bf16_t)(xv[k] * inv);
  if (gb == 0) {
    for (int i = tid; i < 640; i += 256) bar[i] = 0u;  // replay-safe bar reset
  }
}

// ---------------- GEMM: C = A @ B^T, double-buffered LDS ----------------
__global__ __launch_bounds__(256) void gemm_bt(const bf16_t* __restrict__ A,
                                               const bf16_t* __restrict__ B,
                                               float* __restrict__ C,
                                               float* __restrict__ sumArr,
                                               float* __restrict__ sqArr,
                                               float* __restrict__ rmPart) {
  __shared__ __align__(16) bf16_t As[2][128 * 32];
  __shared__ __align__(16) bf16_t Bs[2][128 * 32];
  __shared__ float sred[8];
  int tid = threadIdx.x;
  int wave = tid >> 6, lane = tid & 63;
  int quad = lane >> 4, l16 = lane & 15;
  int bm = blockIdx.y, bn = blockIdx.x;
  int waveM = wave >> 1, waveN = wave & 1;  // 2x2 waves, each 64x64
  floatx4 acc[4][4] = {};

  auto stage = [&](int k0, int buf) {
#pragma unroll
    for (int t = 0; t < 2; t++) {
      int cbase = t * 256 + wave * 64;  // wave-uniform chunk base
      int c = cbase + lane;             // chunk: 16B = 8 bf16
      int row = c >> 2, kc = c & 3;
      gld_lds16(A + (size_t)(bm * 128 + row) * DIM + (k0 + kc * 8),
                (char*)&As[buf][0] + (size_t)cbase * 16);
      gld_lds16(B + (size_t)(bn * 128 + row) * DIM + (k0 + kc * 8),
                (char*)&Bs[buf][0] + (size_t)cbase * 16);
    }
  };

  stage(0, 0);
  asm volatile("s_waitcnt vmcnt(0)" ::: "memory");
  __builtin_amdgcn_s_barrier();
  int cur = 0;
  for (int k0 = 0; k0 < DIM; k0 += 32) {
    if (k0 + 32 < DIM) stage(k0 + 32, cur ^ 1);  // prefetch next while computing
    bf16x8 af[4], bfr[4];
#pragma unroll
    for (int mt = 0; mt < 4; mt++)
      af[mt] = *(const bf16x8*)(&As[cur][0] + (waveM * 64 + mt * 16 + l16) * 32 + quad * 8);
#pragma unroll
    for (int nt = 0; nt < 4; nt++)
      bfr[nt] = *(const bf16x8*)(&Bs[cur][0] + (waveN * 64 + nt * 16 + l16) * 32 + quad * 8);
#pragma unroll
    for (int mt = 0; mt < 4; mt++)
#pragma unroll
      for (int nt = 0; nt < 4; nt++)
        acc[mt][nt] = __builtin_amdgcn_mfma_f32_16x16x32_bf16(af[mt], bfr[nt], acc[mt][nt], 0, 0, 0);
    // ds_reads complete before MFMAs issue (lgkmcnt dep) -> safe to barrier once:
    // drain own prefetch (vmcnt), then barrier protects both buffers' reuse.
    asm volatile("s_waitcnt vmcnt(0)" ::: "memory");
    __builtin_amdgcn_s_barrier();
    cur ^= 1;
  }

  // epilogue: write C (fp32); per-block sum/sq partials; per-(bn,waveN) row maxes.
  // C/D layout (m89-verified): col = lane&15, row = quad*4 + reg
  float lsum = 0.f, lsq = 0.f;
#pragma unroll
  for (int mt = 0; mt < 4; mt++) {
#pragma unroll
    for (int r = 0; r < 4; r++) {
      int gi = bm * 128 + waveM * 64 + mt * 16 + quad * 4 + r;
      float rmax = -3.4e38f;
#pragma unroll
      for (int nt = 0; nt < 4; nt++) {
        float vv = acc[mt][nt][r];
        int gj = bn * 128 + waveN * 64 + nt * 16 + l16;
        C[(size_t)gi * NN + gj] = vv;
        lsum += vv;
        lsq += vv * vv;
        rmax = fmaxf(rmax, vv);
      }
#pragma unroll
      for (int off = 1; off < 16; off <<= 1) rmax = fmaxf(rmax, __shfl_xor(rmax, off, 64));
      if (l16 == 0) rmPart[(size_t)(bn * 2 + waveN) * NN + gi] = rmax;
    }
  }
#pragma unroll
  for (int off = 1; off < 64; off <<= 1) {
    lsum += __shfl_xor(lsum, off, 64);
    lsq += __shfl_xor(lsq, off, 64);
  }
  if (lane == 0) { sred[wave] = lsum; sred[4 + wave] = lsq; }
  __syncthreads();
  if (tid == 0) {
    int bid = bm * 32 + bn;
    sumArr[bid] = sred[0] + sred[1] + sred[2] + sred[3];
    sqArr[bid] = sred[4] + sred[5] + sred[6] + sred[7];
  }
}

// ---------------- rowmax + stats ----------------
__global__ __launch_bounds__(256) void row_stats(const float* __restrict__ sumArr,
                                                 const float* __restrict__ sqArr,
                                                 const float* __restrict__ rmPart,
                                                 float* __restrict__ rowmax,
                                                 float* __restrict__ scal) {
  int tid = threadIdx.x;
  int row = blockIdx.x * 256 + tid;
  float rm = -3.4e38f;
#pragma unroll 8
  for (int p = 0; p < 64; p++) rm = fmaxf(rm, rmPart[(size_t)p * NN + row]);
  rowmax[row] = rm;
  if (blockIdx.x == 0) {
    double ds = (double)sumArr[tid] + (double)sumArr[tid + 256] +
                (double)sumArr[tid + 512] + (double)sumArr[tid + 768];
    double dq = (double)sqArr[tid] + (double)sqArr[tid + 256] +
                (double)sqArr[tid + 512] + (double)sqArr[tid + 768];
#pragma unroll
    for (int off = 1; off < 64; off <<= 1) {
      ds += __shfl_xor(ds, off, 64);
      dq += __shfl_xor(dq, off, 64);
    }
    __shared__ double dr[8];
    int wave = tid >> 6, lane = tid & 63;
    if (lane == 0) { dr[wave] = ds; dr[4 + wave] = dq; }
    __syncthreads();
    if (tid == 0) {
      double sum = dr[0] + dr[1] + dr[2] + dr[3];
      double sumsq = dr[4] + dr[5] + dr[6] + dr[7];
      double Nd = (double)NN * (double)NN;
      double meand = sum / Nd;
      double var = (sumsq - sum * sum / Nd) / (Nd - 1.0);  // ddof=1
      scal[2] = (float)meand;
      scal[3] = (float)(1.0 / sqrt(var));
    }
  }
}

// ---------------- fused persistent Sinkhorn (dual-strip, tree barriers) ------
__global__ __launch_bounds__(SBT, 2) void sinkhorn_full(
    float* __restrict__ Mraw,        // P-slot: raw M in, P out (base out+1)
    float* __restrict__ Mstd,        // M-slot: standardized M out
    const float* __restrict__ scal,  // [2]=mean [3]=inv_std
    const float* __restrict__ rowmax,
    float* __restrict__ u,           // [4096]
    float* __restrict__ t,           // [4096]
    float* __restrict__ s,           // [4096]
    float* __restrict__ lossArr,     // [256]
    uint32_t* __restrict__ bar,      // tree-barrier state
    float* __restrict__ out) {       // out[0] = loss
  __shared__ float red[8 * RPB];
  __shared__ float u_lds[RPB];
  __shared__ float rowmax_l[RPB];
  __shared__ float mdred[8];

  const int b = blockIdx.x;
  const int tid = threadIdx.x;
  const int wave = tid >> 6, lane = tid & 63;
  const int g0 = b * RPB;   // owned rows (kreg/u) AND owned cols (kcol/t)
  const int c0 = tid * 8;   // this thread's col slice (row-matvec, t/md)
  const int r0 = tid * 8;   // this thread's row slice (col-matvec, u-read)
  uint32_t bg = 0;
  const float mean = scal[2], istd = scal[3];

  // ---- phase 0a: kcol = K col-stripe (rows r0..+8 x cols g0..+16), raw M ----
  // (misaligned-float4 loads on out+1-based Mraw: proven OK r2-r4)
  halfx8 kcol[16];  // kcol[rl*2+h] = cols [g0+8h, g0+8h+8) of row r0+rl
  {
    float rmx[8];
    *(float4*)&rmx[0] = *(const float4*)(rowmax + r0);
    *(float4*)&rmx[4] = *(const float4*)(rowmax + r0 + 4);
#pragma unroll
    for (int rl = 0; rl < 8; rl++) {
      const float* mr = Mraw + (size_t)(r0 + rl) * NN + g0;
      float v16[16];
      *(float4*)&v16[0] = *(const float4*)(mr);
      *(float4*)&v16[4] = *(const float4*)(mr + 4);
      *(float4*)&v16[8] = *(const float4*)(mr + 8);
      *(float4*)&v16[12] = *(const float4*)(mr + 12);
      float rm = rmx[rl];
      halfx8 lo, hi;
#pragma unroll
      for (int q = 0; q < 8; q++) {
        lo[q] = (half_t)__expf((v16[q] - rm) * istd);
        hi[q] = (half_t)__expf((v16[8 + q] - rm) * istd);
      }
      kcol[rl * 2] = lo;
      kcol[rl * 2 + 1] = hi;
    }
  }

  // ---- phase 0b: kreg = K row-strip; standardized M -> Mstd (separate slot) ----
  if (tid < RPB) rowmax_l[tid] = rowmax[g0 + tid];
  __syncthreads();
  halfx8 kreg[RPB];
#pragma unroll
  for (int i = 0; i < RPB; i++) {
    float rm = rowmax_l[i];
    const float* mr = Mraw + (size_t)(g0 + i) * NN + c0;
    float* mo = Mstd + (size_t)(g0 + i) * NN + c0;
    float4 a = *(const float4*)mr;
    float4 bb = *(const float4*)(mr + 4);
    float4 sa, sb;
    sa.x = (a.x - mean) * istd;  sa.y = (a.y - mean) * istd;
    sa.z = (a.z - mean) * istd;  sa.w = (a.w - mean) * istd;
    sb.x = (bb.x - mean) * istd; sb.y = (bb.y - mean) * istd;
    sb.z = (bb.z - mean) * istd; sb.w = (bb.w - mean) * istd;
    *(float4*)mo = sa;
    *(float4*)(mo + 4) = sb;
    halfx8 kp;
    kp[0] = (half_t)__expf((a.x - rm) * istd);
    kp[1] = (half_t)__expf((a.y - rm) * istd);
    kp[2] = (half_t)__expf((a.z - rm) * istd);
    kp[3] = (half_t)__expf((a.w - rm) * istd);
    kp[4] = (half_t)__expf((bb.x - rm) * istd);
    kp[5] = (half_t)__expf((bb.y - rm) * istd);
    kp[6] = (half_t)__expf((bb.z - rm) * istd);
    kp[7] = (half_t)__expf((bb.w - rm) * istd);
    kreg[i] = kp;
  }

  float vr[8];
#pragma unroll
  for (int q = 0; q < 8; q++) vr[q] = 1.0f;

  // row-matvec: u[g0..g0+16) = scale / (Krow . v)
  auto row_phase = [&](float scale, bool toLds) {
    float part[RPB];
#pragma unroll
    for (int i = 0; i < RPB; i++) {
      float p = 0.f;
#pragma unroll
      for (int q = 0; q < 8; q++) p += (float)kreg[i][q] * vr[q];
      part[i] = p;
    }
#pragma unroll
    for (int off = 1; off < 64; off <<= 1)
#pragma unroll
      for (int i = 0; i < RPB; i++) part[i] += __shfl_xor(part[i], off, 64);
    if (lane == 0) {
#pragma unroll
      for (int i = 0; i < RPB; i++) red[wave * RPB + i] = part[i];
    }
    __syncthreads();
    if (tid < RPB) {
      float dsum = 0.f;
#pragma unroll
      for (int w = 0; w < 8; w++) dsum += red[w * RPB + tid];
      float uv = scale / dsum;
      u[g0 + tid] = uv;
      if (toLds) u_lds[tid] = uv;
    }
    // no trailing sync needed: gbar follows immediately
  };

  // col-matvec: dst[g0..g0+16) = Kcol^T u (thread covers rows r0..r0+8)
  auto col_phase = [&](float* dst) {
    float u8[8];
    *(float4*)&u8[0] = *(const float4*)(u + r0);
    *(float4*)&u8[4] = *(const float4*)(u + r0 + 4);
    float tp[RPB];
#pragma unroll
    for (int j = 0; j < RPB; j++) tp[j] = 0.f;
#pragma unroll
    for (int rl = 0; rl < 8; rl++) {
      float uv = u8[rl];
#pragma unroll
      for (int q = 0; q < 8; q++) {
        tp[q] += (float)kcol[rl * 2][q] * uv;
        tp[8 + q] += (float)kcol[rl * 2 + 1][q] * uv;
      }
    }
#pragma unroll
    for (int off = 1; off < 64; off <<= 1)
#pragma unroll
      for (int j = 0; j < RPB; j++) tp[j] += __shfl_xor(tp[j], off, 64);
    if (lane == 0) {
#pragma unroll
      for (int j = 0; j < RPB; j++) red[wave * RPB + j] = tp[j];
    }
    __syncthreads();
    if (tid < RPB) {
      float tv = 0.f;
#pragma unroll
      for (int w = 0; w < 8; w++) tv += red[w * RPB + tid];
      dst[g0 + tid] = tv;
    }
  };

  // md over full t, computed redundantly per block (bit-identical everywhere):
  // thread covers t[c0..c0+8) -> block covers all 4096 cols.
  auto mdcheck = [&](float* t8) -> float {
    *(float4*)&t8[0] = *(const float4*)(t + c0);
    *(float4*)&t8[4] = *(const float4*)(t + c0 + 4);
    float dev = 0.f;
#pragma unroll
    for (int q = 0; q < 8; q++) dev = fmaxf(dev, fabsf(vr[q] * t8[q] - RC));
#pragma unroll
    for (int off = 1; off < 64; off <<= 1) dev = fmaxf(dev, __shfl_xor(dev, off, 64));
    if (lane == 0) mdred[wave] = dev;
    __syncthreads();
    float md = mdred[0];
#pragma unroll
    for (int w = 1; w < 8; w++) md = fmaxf(md, mdred[w]);
    __syncthreads();  // mdred free for reuse
    return md;
  };

  // ---- Sinkhorn loop: u = r/(Kv); t = K^T u; maxdev; v = c/t ----
  bool frozen = false;
  for (int it = 0; it < OT_ITERS; it++) {
    if (it > 0) {
      float t8[8];
      float md = mdcheck(t8);
      if (md <= OT_EPS_F) { frozen = true; break; }  // identical in all blocks
#pragma unroll
      for (int q = 0; q < 8; q++) vr[q] = RC / t8[q];
    }
    row_phase(RC, false);
    gbar(bar, ++bg);   // u ready everywhere (also: everyone done reading t)
    col_phase(t);
    gbar(bar, ++bg);   // t ready everywhere (also: everyone done reading u)
  }
  if (!frozen) {  // dev check of the last iteration
    float t8[8];
    float md = mdcheck(t8);
    if (md > OT_EPS_F) {
#pragma unroll
      for (int q = 0; q < 8; q++) vr[q] = RC / t8[q];  // commit final col-normalize v
    }
  }

  // ---- final: w = 1/(Kv); s = K^T w; P_ij = K_ij * w_i / s_j (v cancels) ----
  row_phase(1.0f, true);  // w -> u[] and u_lds
  gbar(bar, ++bg);
  col_phase(s);           // s = K^T w
  gbar(bar, ++bg);

  float s8[8];
  *(float4*)&s8[0] = *(const float4*)(s + c0);
  *(float4*)&s8[4] = *(const float4*)(s + c0 + 4);
  float isv[8];
#pragma unroll
  for (int q = 0; q < 8; q++) isv[q] = 1.0f / s8[q];
  float ls = 0.f;
#pragma unroll
  for (int i = 0; i < RPB; i++) {
    int gi = g0 + i;
    float wi = u_lds[i];
    float* prow = Mraw + (size_t)gi * NN + c0;  // P overwrites raw M (done with it)
    float4 pa, pb;
    float pv[8];
#pragma unroll
    for (int q = 0; q < 8; q++) {
      float p = (float)kreg[i][q] * wi * isv[q];
      pv[q] = p;
      float d = p - ((gi == c0 + q) ? 1.0f : 0.0f);
      ls += d * d;
    }
    pa.x = pv[0]; pa.y = pv[1]; pa.z = pv[2]; pa.w = pv[3];
    pb.x = pv[4]; pb.y = pv[5]; pb.z = pv[6]; pb.w = pv[7];
    *(float4*)prow = pa;
    *(float4*)(prow + 4) = pb;
  }
#pragma unroll
  for (int off = 1; off < 64; off <<= 1) ls += __shfl_xor(ls, off, 64);
  if (lane == 0) red[wave] = ls;
  __syncthreads();
  if (tid == 0) {
    float tot = 0.f;
#pragma unroll
    for (int w = 0; w < 8; w++) tot += red[w];
    lossArr[b] = tot;  // ordered by this thread's own release in gbar
  }
  gbar(bar, ++bg);
  if (b == 0) {
    float lv = (tid < 256) ? lossArr[tid] : 0.f;
#pragma unroll
    for (int off = 1; off < 64; off <<= 1) lv += __shfl_xor(lv, off, 64);
    if (lane == 0) mdred[wave] = lv;
    __syncthreads();
    if (tid == 0) {
      float tot = 0.f;
#pragma unroll
      for (int w = 0; w < 8; w++) tot += mdred[w];
      out[0] = sqrtf(tot);
    }
  }
}

// ---------------- launch ----------------
extern "C" void kernel_launch(void* const* d_in, const int* in_sizes, int n_in, void* d_out,
                              int out_size, void* d_ws, size_t ws_size, hipStream_t stream) {
  const float* ft = (const float*)d_in[0];
  const float* fs = (const float*)d_in[1];
  float* out = (float*)d_out;

  char* ws = (char*)d_ws;
  bf16_t* A = (bf16_t*)ws;                 // 8 MiB
  bf16_t* B = (bf16_t*)(ws + (8u << 20));  // 8 MiB
  float* fbase = (float*)(ws + (16u << 20));
  float* u = fbase;                        // 4096
  float* t = fbase + 4096;                 // 4096
  float* s = fbase + 8192;                 // 4096
  float* rowmax = fbase + 12288;           // 4096
  float* scal = fbase + 16384;             // 8 ([2]=mean [3]=inv_std)
  float* lossArr = fbase + 16640;          // 256
  uint32_t* bar = (uint32_t*)(fbase + 17408);  // 640 words (spaced counters)
  float* sumArr = fbase + 18432;           // 1024
  float* sqArr = fbase + 19456;            // 1024
  float* rmPart = fbase + 20480;           // 64*4096 = 1 MiB

  float* P_slot = out + 1;                     // raw M scratch, then P
  float* M_slot = out + 1 + (size_t)NN * NN;   // standardized M

  norm_rows2<<<2048, 256, 0, stream>>>(ft, fs, A, B, bar);
  gemm_bt<<<dim3(32, 32), 256, 0, stream>>>(A, B, P_slot, sumArr, sqArr, rmPart);
  row_stats<<<16, 256, 0, stream>>>(sumArr, sqArr, rmPart, rowmax, scal);
  sinkhorn_full<<<256, SBT, 0, stream>>>(P_slot, M_slot, scal, rowmax, u, t, s,
                                         lossArr, bar, out);
}

// Round 7
// 406.402 us; speedup vs baseline: 1.0114x; 1.0114x over previous
//
#include <hip/hip_runtime.h>
#include <stdint.h>
#include <math.h>

// OTLoss: ft(4096x1024), fs(4096x1024) fp32 -> (loss, P[4096x4096], M[4096x4096])
//
// Pipeline:
//  1) norm_rows2 (fused): row-normalize ft,fs -> bf16 A,B; block 0 zeroes bar state
//  2) gemm_bt: M_raw = A @ B^T -> ALIGNED ws buffer (r0-r6 wrote to out+1: every
//     load split + partial-line RMW; gemm WRITE was 74MB for a 64MB matrix).
//     Double-buffered LDS (prefetch k+1 before compute k, vmcnt(0)+s_barrier).
//     Epilogue: per-block sum/sq partials + per-(bn,waveN) row maxes.
//  3) row_stats: rowmax[4096]; mean/inv_std (ddof=1, double) -> scal
//  4) sinkhorn_full (PLAIN launch, 256 blocks x 512 thr, co-resident):
//     DUAL-STRIP registers: block b owns strip(b) = (b&7)*32 + (b>>3)
//     (XCD-aware bijection: round-robin dispatch puts b=x mod 8 on XCD x, so
//     same-XCD blocks own ADJACENT 16-col stripes -> shared 128B lines fetched
//     once per XCD; r6's naive mapping double-fetched: FETCH 185MB).
//     kreg = K row-strip, kcol = K col-stripe, both in registers.
//     Per iter: u = r/(Krow v) by owner -> u[4096]; tree-barrier;
//     t = Kcol^T u by owner -> t[4096]; tree-barrier; maxdev computed
//     redundantly per block (bit-identical everywhere, no exchange).
//     Barrier = tree arrival (r2/r3-proven) + 8-LINE gen BROADCAST (r4 showed
//     detection congestion, not arrival, dominates; 32 pollers/line not 256).
//     Final Mstd/P writes to misaligned out slots use SCALAR stores (4B-aligned,
//     no straddle RMW); loss gathered by block 0.

#define NN 4096
#define DIM 1024
#define OT_ITERS 20
#define OT_EPS_F 1e-6f
#define RC (1.0f/4096.0f)
#define RPB 16   // rows/cols owned per block
#define SBT 512  // sinkhorn block threads

typedef __bf16 bf16_t;
typedef _Float16 half_t;
typedef __bf16 bf16x8 __attribute__((ext_vector_type(8)));
typedef _Float16 halfx8 __attribute__((ext_vector_type(8)));
typedef float floatx4 __attribute__((ext_vector_type(4)));

typedef __attribute__((address_space(1))) void gv_t;
typedef __attribute__((address_space(3))) void lv_t;

// async global->LDS, 16B per lane; lds dst = wave-uniform base, HW adds lane*16
__device__ __forceinline__ void gld_lds16(const void* g, void* lds_uniform) {
  uint32_t loff = (uint32_t)(uintptr_t)lds_uniform;
  loff = (uint32_t)__builtin_amdgcn_readfirstlane((int)loff);
  __builtin_amdgcn_global_load_lds((gv_t*)(uintptr_t)g, (lv_t*)(uintptr_t)loff, 16, 0, 0);
}

// ---- tree grid barrier with 8-line gen broadcast ---------------------------
// bar (uint32): cnt[grp] at grp*64 (grp<8), root at 512, gen[grp] at 576+grp*64.
// 1088 words, zeroed each launch by norm_rows2 block 0.
__device__ __forceinline__ void gbar(uint32_t* bar, uint32_t g) {
  __syncthreads();  // drains vmcnt before s_barrier -> this block's stores visible
  if (threadIdx.x == 0) {
    int grp = blockIdx.x >> 5;
    uint32_t* cnt = bar + grp * 64;
    uint32_t* root = bar + 512;
    if (__hip_atomic_fetch_add(cnt, 1u, __ATOMIC_RELEASE, __HIP_MEMORY_SCOPE_AGENT) == 31u) {
      __hip_atomic_store(cnt, 0u, __ATOMIC_RELAXED, __HIP_MEMORY_SCOPE_AGENT);
      if (__hip_atomic_fetch_add(root, 1u, __ATOMIC_ACQ_REL, __HIP_MEMORY_SCOPE_AGENT) == 7u) {
        __hip_atomic_store(root, 0u, __ATOMIC_RELAXED, __HIP_MEMORY_SCOPE_AGENT);
#pragma unroll
        for (int q = 0; q < 8; q++)  // broadcast: 32 pollers/line instead of 256
          __hip_atomic_store(bar + 576 + q * 64, g, __ATOMIC_RELEASE, __HIP_MEMORY_SCOPE_AGENT);
      }
    }
    uint32_t* mygen = bar + 576 + grp * 64;
    while (__hip_atomic_load(mygen, __ATOMIC_RELAXED, __HIP_MEMORY_SCOPE_AGENT) < g)
      __builtin_amdgcn_s_sleep(1);
    __builtin_amdgcn_fence(__ATOMIC_ACQUIRE, "agent");
  }
  __syncthreads();
}

// ---------------- fused row normalize (ft and fs) + bar init ----------------
__global__ __launch_bounds__(256) void norm_rows2(const float* __restrict__ ft,
                                                  const float* __restrict__ fs,
                                                  bf16_t* __restrict__ A,
                                                  bf16_t* __restrict__ B,
                                                  uint32_t* __restrict__ bar) {
  int gb = blockIdx.x;  // 0..2047
  const float* X = (gb < 1024) ? ft : fs;
  bf16_t* Y = (gb < 1024) ? A : B;
  int bb = gb & 1023;
  int tid = threadIdx.x;
  int wave = tid >> 6, lane = tid & 63;
  int row = bb * 4 + wave;
  const float* xr = X + (size_t)row * DIM;
  float xv[16];
  float ss = 0.f;
#pragma unroll
  for (int k = 0; k < 16; k++) { xv[k] = xr[lane + 64 * k]; ss += xv[k] * xv[k]; }
#pragma unroll
  for (int off = 1; off < 64; off <<= 1) ss += __shfl_xor(ss, off, 64);
  float inv = rsqrtf(ss);  // norm ~ 32 >> 1e-12 floor, floor never binds
  bf16_t* yr = Y + (size_t)row * DIM;
#pragma unroll
  for (int k = 0; k < 16; k++) yr[lane + 64 * k] = (bf16_t)(xv[k] * inv);
  if (gb == 0) {
    for (int i = tid; i < 1088; i += 256) bar[i] = 0u;  // replay-safe bar reset
  }
}

// ---------------- GEMM: C = A @ B^T, double-buffered LDS, aligned C ----------
__global__ __launch_bounds__(256) void gemm_bt(const bf16_t* __restrict__ A,
                                               const bf16_t* __restrict__ B,
                                               float* __restrict__ C,
                                               float* __restrict__ sumArr,
                                               float* __restrict__ sqArr,
                                               float* __restrict__ rmPart) {
  __shared__ __align__(16) bf16_t As[2][128 * 32];
  __shared__ __align__(16) bf16_t Bs[2][128 * 32];
  __shared__ float sred[8];
  int tid = threadIdx.x;
  int wave = tid >> 6, lane = tid & 63;
  int quad = lane >> 4, l16 = lane & 15;
  int bm = blockIdx.y, bn = blockIdx.x;
  int waveM = wave >> 1, waveN = wave & 1;  // 2x2 waves, each 64x64
  floatx4 acc[4][4] = {};

  auto stage = [&](int k0, int buf) {
#pragma unroll
    for (int t = 0; t < 2; t++) {
      int cbase = t * 256 + wave * 64;  // wave-uniform chunk base
      int c = cbase + lane;             // chunk: 16B = 8 bf16
      int row = c >> 2, kc = c & 3;
      gld_lds16(A + (size_t)(bm * 128 + row) * DIM + (k0 + kc * 8),
                (char*)&As[buf][0] + (size_t)cbase * 16);
      gld_lds16(B + (size_t)(bn * 128 + row) * DIM + (k0 + kc * 8),
                (char*)&Bs[buf][0] + (size_t)cbase * 16);
    }
  };

  stage(0, 0);
  asm volatile("s_waitcnt vmcnt(0)" ::: "memory");
  __builtin_amdgcn_s_barrier();
  int cur = 0;
  for (int k0 = 0; k0 < DIM; k0 += 32) {
    if (k0 + 32 < DIM) stage(k0 + 32, cur ^ 1);  // prefetch next while computing
    bf16x8 af[4], bfr[4];
#pragma unroll
    for (int mt = 0; mt < 4; mt++)
      af[mt] = *(const bf16x8*)(&As[cur][0] + (waveM * 64 + mt * 16 + l16) * 32 + quad * 8);
#pragma unroll
    for (int nt = 0; nt < 4; nt++)
      bfr[nt] = *(const bf16x8*)(&Bs[cur][0] + (waveN * 64 + nt * 16 + l16) * 32 + quad * 8);
#pragma unroll
    for (int mt = 0; mt < 4; mt++)
#pragma unroll
      for (int nt = 0; nt < 4; nt++)
        acc[mt][nt] = __builtin_amdgcn_mfma_f32_16x16x32_bf16(af[mt], bfr[nt], acc[mt][nt], 0, 0, 0);
    asm volatile("s_waitcnt vmcnt(0)" ::: "memory");
    __builtin_amdgcn_s_barrier();
    cur ^= 1;
  }

  // epilogue: write C (aligned fp32); per-block sum/sq; per-(bn,waveN) row maxes.
  // C/D layout (m89-verified): col = lane&15, row = quad*4 + reg
  float lsum = 0.f, lsq = 0.f;
#pragma unroll
  for (int mt = 0; mt < 4; mt++) {
#pragma unroll
    for (int r = 0; r < 4; r++) {
      int gi = bm * 128 + waveM * 64 + mt * 16 + quad * 4 + r;
      float rmax = -3.4e38f;
#pragma unroll
      for (int nt = 0; nt < 4; nt++) {
        float vv = acc[mt][nt][r];
        int gj = bn * 128 + waveN * 64 + nt * 16 + l16;
        C[(size_t)gi * NN + gj] = vv;
        lsum += vv;
        lsq += vv * vv;
        rmax = fmaxf(rmax, vv);
      }
#pragma unroll
      for (int off = 1; off < 16; off <<= 1) rmax = fmaxf(rmax, __shfl_xor(rmax, off, 64));
      if (l16 == 0) rmPart[(size_t)(bn * 2 + waveN) * NN + gi] = rmax;
    }
  }
#pragma unroll
  for (int off = 1; off < 64; off <<= 1) {
    lsum += __shfl_xor(lsum, off, 64);
    lsq += __shfl_xor(lsq, off, 64);
  }
  if (lane == 0) { sred[wave] = lsum; sred[4 + wave] = lsq; }
  __syncthreads();
  if (tid == 0) {
    int bid = bm * 32 + bn;
    sumArr[bid] = sred[0] + sred[1] + sred[2] + sred[3];
    sqArr[bid] = sred[4] + sred[5] + sred[6] + sred[7];
  }
}

// ---------------- rowmax + stats ----------------
__global__ __launch_bounds__(256) void row_stats(const float* __restrict__ sumArr,
                                                 const float* __restrict__ sqArr,
                                                 const float* __restrict__ rmPart,
                                                 float* __restrict__ rowmax,
                                                 float* __restrict__ scal) {
  int tid = threadIdx.x;
  int row = blockIdx.x * 256 + tid;
  float rm = -3.4e38f;
#pragma unroll 8
  for (int p = 0; p < 64; p++) rm = fmaxf(rm, rmPart[(size_t)p * NN + row]);
  rowmax[row] = rm;
  if (blockIdx.x == 0) {
    double ds = (double)sumArr[tid] + (double)sumArr[tid + 256] +
                (double)sumArr[tid + 512] + (double)sumArr[tid + 768];
    double dq = (double)sqArr[tid] + (double)sqArr[tid + 256] +
                (double)sqArr[tid + 512] + (double)sqArr[tid + 768];
#pragma unroll
    for (int off = 1; off < 64; off <<= 1) {
      ds += __shfl_xor(ds, off, 64);
      dq += __shfl_xor(dq, off, 64);
    }
    __shared__ double dr[8];
    int wave = tid >> 6, lane = tid & 63;
    if (lane == 0) { dr[wave] = ds; dr[4 + wave] = dq; }
    __syncthreads();
    if (tid == 0) {
      double sum = dr[0] + dr[1] + dr[2] + dr[3];
      double sumsq = dr[4] + dr[5] + dr[6] + dr[7];
      double Nd = (double)NN * (double)NN;
      double meand = sum / Nd;
      double var = (sumsq - sum * sum / Nd) / (Nd - 1.0);  // ddof=1
      scal[2] = (float)meand;
      scal[3] = (float)(1.0 / sqrt(var));
    }
  }
}

// ---------------- fused persistent Sinkhorn (dual-strip, tree barriers) ------
__global__ __launch_bounds__(SBT, 2) void sinkhorn_full(
    const float* __restrict__ Mraw,  // aligned ws (or P-slot fallback)
    float* __restrict__ Pout,        // P output slot (out+1, misaligned: scalar stores)
    float* __restrict__ Mstd,        // M output slot (misaligned: scalar stores)
    const float* __restrict__ scal,  // [2]=mean [3]=inv_std
    const float* __restrict__ rowmax,
    float* __restrict__ u,           // [4096]
    float* __restrict__ t,           // [4096]
    float* __restrict__ s,           // [4096]
    float* __restrict__ lossArr,     // [256]
    uint32_t* __restrict__ bar,      // tree-barrier state
    float* __restrict__ out) {       // out[0] = loss
  __shared__ float red[8 * RPB];
  __shared__ float u_lds[RPB];
  __shared__ float rowmax_l[RPB];
  __shared__ float mdred[8];

  const int b = blockIdx.x;
  const int tid = threadIdx.x;
  const int wave = tid >> 6, lane = tid & 63;
  // XCD-aware strip ownership: same-XCD blocks (b mod 8) own adjacent stripes
  const int strip = (b & 7) * 32 + (b >> 3);  // bijective [0,256)
  const int g0 = strip * RPB;  // owned rows (kreg/u) AND owned cols (kcol/t)
  const int c0 = tid * 8;      // this thread's col slice (row-matvec, t/md)
  const int r0 = tid * 8;      // this thread's row slice (col-matvec, u-read)
  uint32_t bg = 0;
  const float mean = scal[2], istd = scal[3];

  // ---- phase 0a: kcol = K col-stripe (rows r0..+8 x cols g0..+16), aligned ----
  halfx8 kcol[16];  // kcol[rl*2+h] = cols [g0+8h, g0+8h+8) of row r0+rl
  {
    float rmx[8];
    *(float4*)&rmx[0] = *(const float4*)(rowmax + r0);
    *(float4*)&rmx[4] = *(const float4*)(rowmax + r0 + 4);
#pragma unroll
    for (int rl = 0; rl < 8; rl++) {
      const float* mr = Mraw + (size_t)(r0 + rl) * NN + g0;
      float v16[16];
      *(float4*)&v16[0] = *(const float4*)(mr);
      *(float4*)&v16[4] = *(const float4*)(mr + 4);
      *(float4*)&v16[8] = *(const float4*)(mr + 8);
      *(float4*)&v16[12] = *(const float4*)(mr + 12);
      float rm = rmx[rl];
      halfx8 lo, hi;
#pragma unroll
      for (int q = 0; q < 8; q++) {
        lo[q] = (half_t)__expf((v16[q] - rm) * istd);
        hi[q] = (half_t)__expf((v16[8 + q] - rm) * istd);
      }
      kcol[rl * 2] = lo;
      kcol[rl * 2 + 1] = hi;
    }
  }

  // ---- phase 0b: kreg = K row-strip; standardized M -> Mstd (scalar stores) ----
  if (tid < RPB) rowmax_l[tid] = rowmax[g0 + tid];
  __syncthreads();
  halfx8 kreg[RPB];
#pragma unroll
  for (int i = 0; i < RPB; i++) {
    float rm = rowmax_l[i];
    const float* mr = Mraw + (size_t)(g0 + i) * NN + c0;
    float* mo = Mstd + (size_t)(g0 + i) * NN + c0;
    float4 a = *(const float4*)mr;
    float4 bb = *(const float4*)(mr + 4);
    mo[0] = (a.x - mean) * istd;  mo[1] = (a.y - mean) * istd;
    mo[2] = (a.z - mean) * istd;  mo[3] = (a.w - mean) * istd;
    mo[4] = (bb.x - mean) * istd; mo[5] = (bb.y - mean) * istd;
    mo[6] = (bb.z - mean) * istd; mo[7] = (bb.w - mean) * istd;
    halfx8 kp;
    kp[0] = (half_t)__expf((a.x - rm) * istd);
    kp[1] = (half_t)__expf((a.y - rm) * istd);
    kp[2] = (half_t)__expf((a.z - rm) * istd);
    kp[3] = (half_t)__expf((a.w - rm) * istd);
    kp[4] = (half_t)__expf((bb.x - rm) * istd);
    kp[5] = (half_t)__expf((bb.y - rm) * istd);
    kp[6] = (half_t)__expf((bb.z - rm) * istd);
    kp[7] = (half_t)__expf((bb.w - rm) * istd);
    kreg[i] = kp;
  }

  float vr[8];
#pragma unroll
  for (int q = 0; q < 8; q++) vr[q] = 1.0f;

  // row-matvec: u[g0..g0+16) = scale / (Krow . v)
  auto row_phase = [&](float scale, bool toLds) {
    float part[RPB];
#pragma unroll
    for (int i = 0; i < RPB; i++) {
      float p = 0.f;
#pragma unroll
      for (int q = 0; q < 8; q++) p += (float)kreg[i][q] * vr[q];
      part[i] = p;
    }
#pragma unroll
    for (int off = 1; off < 64; off <<= 1)
#pragma unroll
      for (int i = 0; i < RPB; i++) part[i] += __shfl_xor(part[i], off, 64);
    if (lane == 0) {
#pragma unroll
      for (int i = 0; i < RPB; i++) red[wave * RPB + i] = part[i];
    }
    __syncthreads();
    if (tid < RPB) {
      float dsum = 0.f;
#pragma unroll
      for (int w = 0; w < 8; w++) dsum += red[w * RPB + tid];
      float uv = scale / dsum;
      u[g0 + tid] = uv;
      if (toLds) u_lds[tid] = uv;
    }
    // no trailing sync: gbar follows immediately
  };

  // col-matvec: dst[g0..g0+16) = Kcol^T u (thread covers rows r0..r0+8)
  auto col_phase = [&](float* dst) {
    float u8[8];
    *(float4*)&u8[0] = *(const float4*)(u + r0);
    *(float4*)&u8[4] = *(const float4*)(u + r0 + 4);
    float tp[RPB];
#pragma unroll
    for (int j = 0; j < RPB; j++) tp[j] = 0.f;
#pragma unroll
    for (int rl = 0; rl < 8; rl++) {
      float uv = u8[rl];
#pragma unroll
      for (int q = 0; q < 8; q++) {
        tp[q] += (float)kcol[rl * 2][q] * uv;
        tp[8 + q] += (float)kcol[rl * 2 + 1][q] * uv;
      }
    }
#pragma unroll
    for (int off = 1; off < 64; off <<= 1)
#pragma unroll
      for (int j = 0; j < RPB; j++) tp[j] += __shfl_xor(tp[j], off, 64);
    if (lane == 0) {
#pragma unroll
      for (int j = 0; j < RPB; j++) red[wave * RPB + j] = tp[j];
    }
    __syncthreads();
    if (tid < RPB) {
      float tv = 0.f;
#pragma unroll
      for (int w = 0; w < 8; w++) tv += red[w * RPB + tid];
      dst[g0 + tid] = tv;
    }
  };

  // md over full t, redundant per block (bit-identical everywhere)
  auto mdcheck = [&](float* t8) -> float {
    *(float4*)&t8[0] = *(const float4*)(t + c0);
    *(float4*)&t8[4] = *(const float4*)(t + c0 + 4);
    float dev = 0.f;
#pragma unroll
    for (int q = 0; q < 8; q++) dev = fmaxf(dev, fabsf(vr[q] * t8[q] - RC));
#pragma unroll
    for (int off = 1; off < 64; off <<= 1) dev = fmaxf(dev, __shfl_xor(dev, off, 64));
    if (lane == 0) mdred[wave] = dev;
    __syncthreads();
    float md = mdred[0];
#pragma unroll
    for (int w = 1; w < 8; w++) md = fmaxf(md, mdred[w]);
    __syncthreads();  // mdred free for reuse
    return md;
  };

  // ---- Sinkhorn loop: u = r/(Kv); t = K^T u; maxdev; v = c/t ----
  bool frozen = false;
  for (int it = 0; it < OT_ITERS; it++) {
    if (it > 0) {
      float t8[8];
      float md = mdcheck(t8);
      if (md <= OT_EPS_F) { frozen = true; break; }  // identical in all blocks
#pragma unroll
      for (int q = 0; q < 8; q++) vr[q] = RC / t8[q];
    }
    row_phase(RC, false);
    gbar(bar, ++bg);   // u ready everywhere (also: everyone done reading t)
    col_phase(t);
    gbar(bar, ++bg);   // t ready everywhere (also: everyone done reading u)
  }
  if (!frozen) {  // dev check of the last iteration
    float t8[8];
    float md = mdcheck(t8);
    if (md > OT_EPS_F) {
#pragma unroll
      for (int q = 0; q < 8; q++) vr[q] = RC / t8[q];  // commit final col-normalize v
    }
  }

  // ---- final: w = 1/(Kv); s = K^T w; P_ij = K_ij * w_i / s_j (v cancels) ----
  row_phase(1.0f, true);  // w -> u[] and u_lds
  gbar(bar, ++bg);
  col_phase(s);           // s = K^T w
  gbar(bar, ++bg);

  float s8[8];
  *(float4*)&s8[0] = *(const float4*)(s + c0);
  *(float4*)&s8[4] = *(const float4*)(s + c0 + 4);
  float isv[8];
#pragma unroll
  for (int q = 0; q < 8; q++) isv[q] = 1.0f / s8[q];
  float ls = 0.f;
#pragma unroll
  for (int i = 0; i < RPB; i++) {
    int gi = g0 + i;
    float wi = u_lds[i];
    float* prow = Pout + (size_t)gi * NN + c0;  // misaligned base: scalar stores
#pragma unroll
    for (int q = 0; q < 8; q++) {
      float p = (float)kreg[i][q] * wi * isv[q];
      prow[q] = p;
      float d = p - ((gi == c0 + q) ? 1.0f : 0.0f);
      ls += d * d;
    }
  }
#pragma unroll
  for (int off = 1; off < 64; off <<= 1) ls += __shfl_xor(ls, off, 64);
  if (lane == 0) red[wave] = ls;
  __syncthreads();
  if (tid == 0) {
    float tot = 0.f;
#pragma unroll
    for (int w = 0; w < 8; w++) tot += red[w];
    lossArr[b] = tot;  // ordered by this thread's own release in gbar
  }
  gbar(bar, ++bg);
  if (b == 0) {
    float lv = (tid < 256) ? lossArr[tid] : 0.f;
#pragma unroll
    for (int off = 1; off < 64; off <<= 1) lv += __shfl_xor(lv, off, 64);
    if (lane == 0) mdred[wave] = lv;
    __syncthreads();
    if (tid == 0) {
      float tot = 0.f;
#pragma unroll
      for (int w = 0; w < 8; w++) tot += mdred[w];
      out[0] = sqrtf(tot);
    }
  }
}

// ---------------- launch ----------------
extern "C" void kernel_launch(void* const* d_in, const int* in_sizes, int n_in, void* d_out,
                              int out_size, void* d_ws, size_t ws_size, hipStream_t stream) {
  const float* ft = (const float*)d_in[0];
  const float* fs = (const float*)d_in[1];
  float* out = (float*)d_out;

  char* ws = (char*)d_ws;
  bf16_t* A = (bf16_t*)ws;                 // 8 MiB
  bf16_t* B = (bf16_t*)(ws + (8u << 20));  // 8 MiB
  float* fbase = (float*)(ws + (16u << 20));
  float* u = fbase;                        // 4096
  float* t = fbase + 4096;                 // 4096
  float* s = fbase + 8192;                 // 4096
  float* rowmax = fbase + 12288;           // 4096
  float* scal = fbase + 16384;             // 8 ([2]=mean [3]=inv_std)
  float* lossArr = fbase + 16640;          // 256
  uint32_t* bar = (uint32_t*)(fbase + 16896);  // 1088 words (cnt/root/gen lines)
  float* sumArr = fbase + 18432;           // 1024
  float* sqArr = fbase + 19456;            // 1024
  float* rmPart = fbase + 20480;           // 64*4096 = 1 MiB

  float* P_slot = out + 1;                     // P output (misaligned base)
  float* M_slot = out + 1 + (size_t)NN * NN;   // standardized M output (misaligned)

  // aligned M_raw staging if workspace allows; else r6 fallback (raw in P slot)
  float* Mws = (ws_size >= (96ull << 20)) ? (float*)(ws + (32u << 20)) : P_slot;

  norm_rows2<<<2048, 256, 0, stream>>>(ft, fs, A, B, bar);
  gemm_bt<<<dim3(32, 32), 256, 0, stream>>>(A, B, Mws, sumArr, sqArr, rmPart);
  row_stats<<<16, 256, 0, stream>>>(sumArr, sqArr, rmPart, rowmax, scal);
  sinkhorn_full<<<256, SBT, 0, stream>>>(Mws, P_slot, M_slot, scal, rowmax, u, t, s,
                                         lossArr, bar, out);
}